// Round 11
// baseline (262.173 us; speedup 1.0000x reference)
//
#include <hip/hip_runtime.h>
#include <cstdint>
#include <cstddef>

typedef _Float16 half8 __attribute__((ext_vector_type(8)));
typedef __fp16 fp16x2 __attribute__((ext_vector_type(2)));
typedef float floatx16 __attribute__((ext_vector_type(16)));

// ws: frag-linear weight blobs. chunk = 1024 B = 64 lanes x 8 f16, lane l holds
// A[row = tile*32 + (l&31)][k = kchunk*16 + (l>>5)*8 + i], i=0..7.
//   W0c [C][16 chunks]  @ f16 0       (mt 0..3) x (ks 0..3); k<48: W0[(16+k)*128+j],
//                                     k==48: cbias(c,j)=b0[j]+emb_c.W0[0:16,j], else 0
//   W1  [36 chunks]     @ C*8192      (mt 0..3) x (ks 0..8); k<128: W1[k*128+j], k==128: b1[j], else 0
//   W2  [9 chunks]      @ C*8192+18432  (ks 0..8); o=(l&31): o<3 ? (k<128? W2[k*3+o] : k==128? b2[o] : 0) : 0

__global__ void vdc_prep_kernel(const float* __restrict__ W0,
                                const float* __restrict__ W1,
                                const float* __restrict__ W2,
                                const float* __restrict__ b0,
                                const float* __restrict__ b1,
                                const float* __restrict__ b2,
                                const float* __restrict__ emb_tab,
                                const int* __restrict__ embed_ids,
                                int C,
                                _Float16* __restrict__ ws) {
    int i = blockIdx.x * 256 + threadIdx.x;
    int w0end = C * 8192;
    int w1end = w0end + 18432;
    int w2end = w1end + 4608;
    float v = 0.0f;
    if (i < w0end) {
        int c = i >> 13, r = i & 8191;
        int ci = r >> 9, l = (r >> 3) & 63, ii = r & 7;
        int mt = ci >> 2, ks = ci & 3;
        int j  = mt * 32 + (l & 31);
        int kk = ks * 16 + (l >> 5) * 8 + ii;
        if (kk < 48) v = W0[(16 + kk) * 128 + j];
        else if (kk == 48) {
            int id = embed_ids[c];
            v = b0[j];
            #pragma unroll
            for (int e = 0; e < 16; ++e)
                v += emb_tab[(size_t)id * 16 + e] * W0[e * 128 + j];
        }
        ws[i] = (_Float16)v;
    } else if (i < w1end) {
        int r = i - w0end;
        int ci = r >> 9, l = (r >> 3) & 63, ii = r & 7;
        int mt = ci / 9, ks = ci - mt * 9;
        int j  = mt * 32 + (l & 31);
        int kk = ks * 16 + (l >> 5) * 8 + ii;
        if (kk < 128) v = W1[kk * 128 + j];
        else if (kk == 128) v = b1[j];
        ws[i] = (_Float16)v;
    } else if (i < w2end) {
        int r = i - w1end;
        int ks = r >> 9, l = (r >> 3) & 63, ii = r & 7;
        int o  = l & 31;
        int kk = ks * 16 + (l >> 5) * 8 + ii;
        if (o < 3) {
            if (kk < 128) v = W2[kk * 3 + o];
            else if (kk == 128) v = b2[o];
        }
        ws[i] = (_Float16)v;
    }
}

union U4 { unsigned u[4]; half8 h; };

__device__ __forceinline__ unsigned pkr(float a, float b) {
    union { fp16x2 h; unsigned u; } x;
    x.h = __builtin_amdgcn_cvt_pkrtz(a, b);
    return x.u;
}

__device__ __forceinline__ floatx16 zero16() {
    floatx16 z;
    #pragma unroll
    for (int r = 0; r < 16; ++r) z[r] = 0.0f;
    return z;
}

// acc tile (C-layout) -> two B-frag half8 chunks via relu+pack+lane^32 exchange.
__device__ __forceinline__ void transition(const floatx16& a, int hl,
                                           half8& lo, half8& hi) {
    unsigned p0 = pkr(fmaxf(a[0],  0.f), fmaxf(a[1],  0.f));
    unsigned p1 = pkr(fmaxf(a[2],  0.f), fmaxf(a[3],  0.f));
    unsigned p2 = pkr(fmaxf(a[4],  0.f), fmaxf(a[5],  0.f));
    unsigned p3 = pkr(fmaxf(a[6],  0.f), fmaxf(a[7],  0.f));
    unsigned p4 = pkr(fmaxf(a[8],  0.f), fmaxf(a[9],  0.f));
    unsigned p5 = pkr(fmaxf(a[10], 0.f), fmaxf(a[11], 0.f));
    unsigned p6 = pkr(fmaxf(a[12], 0.f), fmaxf(a[13], 0.f));
    unsigned p7 = pkr(fmaxf(a[14], 0.f), fmaxf(a[15], 0.f));
    unsigned r0 = __shfl_xor(hl ? p0 : p2, 32);
    unsigned r1 = __shfl_xor(hl ? p1 : p3, 32);
    unsigned r2 = __shfl_xor(hl ? p4 : p6, 32);
    unsigned r3 = __shfl_xor(hl ? p5 : p7, 32);
    U4 L, H;
    L.u[0] = hl ? r0 : p0;
    L.u[1] = hl ? r1 : p1;
    L.u[2] = hl ? p2 : r0;
    L.u[3] = hl ? p3 : r1;
    H.u[0] = hl ? r2 : p4;
    H.u[1] = hl ? r3 : p5;
    H.u[2] = hl ? p6 : r2;
    H.u[3] = hl ? p7 : r3;
    lo = L.h; hi = H.h;
}

// build layer0 B-operand frags (feats chunks 0,1 + SH chunk 2) for element n
__device__ __forceinline__ void build_bfrags(
    const float* __restrict__ feats, const float* __restrict__ dirs,
    size_t cN, int n, int hl, int nbu,
    half8& o0, half8& o1, half8& o2)
{
    const float* fp = feats + (size_t)n * 32 + hl * 8;
    float4 f0 = *(const float4*)(fp);
    float4 f1 = *(const float4*)(fp + 4);
    float4 f2 = *(const float4*)(fp + 16);
    float4 f3 = *(const float4*)(fp + 20);
    U4 u0, u1;
    u0.u[0] = pkr(f0.x, f0.y); u0.u[1] = pkr(f0.z, f0.w);
    u0.u[2] = pkr(f1.x, f1.y); u0.u[3] = pkr(f1.z, f1.w);
    u1.u[0] = pkr(f2.x, f2.y); u1.u[1] = pkr(f2.z, f2.w);
    u1.u[2] = pkr(f3.x, f3.y); u1.u[3] = pkr(f3.z, f3.w);
    o0 = u0.h; o1 = u1.h;

    const float* dp = dirs + (cN + n) * 3;
    float dx = dp[0], dy = dp[1], dz = dp[2];
    float nrm = sqrtf(dx * dx + dy * dy + dz * dz);
    float inv = 1.0f / fmaxf(nrm, 1e-12f);
    float x = dx * inv, y = dy * inv, z = dz * inv;

    float z2     = z * z;
    float fTmp0B = -1.092548430592079f * z;
    float fC1    = x * x - y * y;
    float fS1    = 2.0f * x * y;
    float fTmp0C = -2.285228997322329f * z2 + 0.4570457994644658f;
    float fTmp1B = 1.445305721320277f * z;
    float fC2    = x * fC1 - y * fS1;
    float fS2    = x * fS1 + y * fC1;

    float sh[16];
    sh[0]  = 0.2820947917738781f;
    sh[1]  = -0.48860251190292f * y;
    sh[2]  = 0.48860251190292f * z;
    sh[3]  = -0.48860251190292f * x;
    sh[4]  = 0.5462742152960395f * fS1;
    sh[5]  = fTmp0B * y;
    sh[6]  = 0.9461746957575601f * z2 - 0.3153915652525201f;
    sh[7]  = fTmp0B * x;
    sh[8]  = 0.5462742152960395f * fC1;
    sh[9]  = -0.5900435899266435f * fS2;
    sh[10] = fTmp1B * fS1;
    sh[11] = fTmp0C * y;
    sh[12] = z * (1.865881662950577f * z2 - 1.119528997770346f);
    sh[13] = fTmp0C * x;
    sh[14] = fTmp1B * fC1;
    sh[15] = -0.5900435899266435f * fC2;
    #pragma unroll
    for (int i = 0; i < 16; ++i) if (i >= nbu) sh[i] = 0.0f;

    float s0 = hl ? sh[8]  : sh[0];
    float s1 = hl ? sh[9]  : sh[1];
    float s2 = hl ? sh[10] : sh[2];
    float s3 = hl ? sh[11] : sh[3];
    float s4 = hl ? sh[12] : sh[4];
    float s5 = hl ? sh[13] : sh[5];
    float s6 = hl ? sh[14] : sh[6];
    float s7 = hl ? sh[15] : sh[7];
    U4 u2;
    u2.u[0] = pkr(s0, s1); u2.u[1] = pkr(s2, s3);
    u2.u[2] = pkr(s4, s5); u2.u[3] = pkr(s6, s7);
    o2 = u2.h;
}

#define MFMA(a, b, c) __builtin_amdgcn_mfma_f32_32x32x16_f16((a), (b), (c), 0, 0, 0)
#define LDF(off) (*(const half8*)(fr + (off)))

// layer 0, one 32-row weight tile MT, both element tiles (a and b)
#define L0_MT(MT, HA0, HA1, HB0, HB1)                                    \
    do {                                                                 \
        half8 a0 = LDF(((MT) * 4 + 0) * 1024);                           \
        half8 a1 = LDF(((MT) * 4 + 1) * 1024);                           \
        half8 a2 = LDF(((MT) * 4 + 2) * 1024);                           \
        half8 a3 = LDF(((MT) * 4 + 3) * 1024);                           \
        floatx16 acc = zero16();                                         \
        acc = MFMA(a0, ax0, acc); acc = MFMA(a1, ax1, acc);              \
        acc = MFMA(a2, ax2, acc); acc = MFMA(a3, bbias, acc);            \
        transition(acc, hl, HA0, HA1);                                   \
        acc = zero16();                                                  \
        acc = MFMA(a0, bx0, acc); acc = MFMA(a1, bx1, acc);              \
        acc = MFMA(a2, bx2, acc); acc = MFMA(a3, bbias, acc);            \
        transition(acc, hl, HB0, HB1);                                   \
    } while (0)

// layer 1 (+ fused layer 2) for one 32-row W1 tile MT, both element tiles
#define L1_MT(MT)                                                        \
    do {                                                                 \
        half8 q0 = LDF(16384 + ((MT) * 9 + 0) * 1024);                   \
        half8 q1 = LDF(16384 + ((MT) * 9 + 1) * 1024);                   \
        half8 q2 = LDF(16384 + ((MT) * 9 + 2) * 1024);                   \
        half8 q3 = LDF(16384 + ((MT) * 9 + 3) * 1024);                   \
        half8 q4 = LDF(16384 + ((MT) * 9 + 4) * 1024);                   \
        half8 q5 = LDF(16384 + ((MT) * 9 + 5) * 1024);                   \
        half8 q6 = LDF(16384 + ((MT) * 9 + 6) * 1024);                   \
        half8 q7 = LDF(16384 + ((MT) * 9 + 7) * 1024);                   \
        half8 q8 = LDF(16384 + ((MT) * 9 + 8) * 1024);                   \
        half8 w2a = LDF(53248 + (2 * (MT) + 0) * 1024);                  \
        half8 w2b = LDF(53248 + (2 * (MT) + 1) * 1024);                  \
        floatx16 acc = zero16();                                         \
        acc = MFMA(q0, ha0, acc); acc = MFMA(q1, ha1, acc);              \
        acc = MFMA(q2, ha2, acc); acc = MFMA(q3, ha3, acc);              \
        acc = MFMA(q4, ha4, acc); acc = MFMA(q5, ha5, acc);              \
        acc = MFMA(q6, ha6, acc); acc = MFMA(q7, ha7, acc);              \
        acc = MFMA(q8, bbias, acc);                                      \
        half8 g0, g1;                                                    \
        transition(acc, hl, g0, g1);                                     \
        acc3a = MFMA(w2a, g0, acc3a); acc3a = MFMA(w2b, g1, acc3a);      \
        acc = zero16();                                                  \
        acc = MFMA(q0, hb0, acc); acc = MFMA(q1, hb1, acc);              \
        acc = MFMA(q2, hb2, acc); acc = MFMA(q3, hb3, acc);              \
        acc = MFMA(q4, hb4, acc); acc = MFMA(q5, hb5, acc);              \
        acc = MFMA(q6, hb6, acc); acc = MFMA(q7, hb7, acc);              \
        acc = MFMA(q8, bbias, acc);                                      \
        transition(acc, hl, g0, g1);                                     \
        acc3b = MFMA(w2a, g0, acc3b); acc3b = MFMA(w2b, g1, acc3b);      \
    } while (0)

// LDS frag arena: W0c chunks 0..15 @0, W1 @16384, W2 @53248. 62464 B.
// 512 threads = 8 waves; each wave owns 64 elements (2 B-tiles, EPW=2).
// __launch_bounds__(512,4): 128-reg cap (actual use 88 — R10-verified) ->
// 2 blocks/CU x 8 waves = 16 waves/CU = 4 waves/SIMD for latency hiding.
__global__ __launch_bounds__(512, 4) void vdc_mlp_kernel(
    const float* __restrict__ feats,      // [N,32]
    const float* __restrict__ dirs,       // [C,N,3]
    const int* __restrict__ sh_deg_p,     // [1]
    const _Float16* __restrict__ ws,
    float* __restrict__ out,              // [C,N,3]
    int N, int C)
{
    __shared__ uint4 arena[3904];         // 62464 B
    char* lds = (char*)arena;

    const int tid   = threadIdx.x;
    const int c     = blockIdx.y;
    const int w     = tid >> 6;           // 0..7
    const int lane  = tid & 63;
    const int ln    = lane & 31;
    const int hl    = lane >> 5;
    const int base  = blockIdx.x * 512 + w * 64;   // this wave's 64 elements

    // ---- stage frag-linear weights into LDS (coalesced, conflict-free) ----
    {
        const uint4* srcA = (const uint4*)(ws + (size_t)c * 8192);
        const uint4* srcB = (const uint4*)(ws + (size_t)C * 8192);
        #pragma unroll
        for (int it = 0; it < 8; ++it) {
            int idx = it * 512 + tid;
            if (idx < 3904)
                arena[idx] = (idx < 1024) ? srcA[idx] : srcB[idx - 1024];
        }
    }

    // ---- build layer0 B-frags for both element tiles (overlaps staging) ----
    half8 bbias;
    {
        U4 ub;
        ub.u[0] = hl ? 0u : 0x00003C00u;   // f16 1.0 at k-offset 0, hl=0 only
        ub.u[1] = 0u; ub.u[2] = 0u; ub.u[3] = 0u;
        bbias = ub.h;
    }
    int deg = sh_deg_p[0];
    int nbu = (deg + 1) * (deg + 1);
    int na = base + ln;      if (na >= N) na = N - 1;
    int nb = base + 32 + ln; if (nb >= N) nb = N - 1;
    half8 ax0, ax1, ax2, bx0, bx1, bx2;
    build_bfrags(feats, dirs, (size_t)c * N, na, hl, nbu, ax0, ax1, ax2);
    build_bfrags(feats, dirs, (size_t)c * N, nb, hl, nbu, bx0, bx1, bx2);

    __syncthreads();

    const char* fr = lds + lane * 16;     // per-lane frag base; chunk offsets imm

    // ---- layer 0 + transitions (named h-frags) ----
    half8 ha0, ha1, ha2, ha3, ha4, ha5, ha6, ha7;
    half8 hb0, hb1, hb2, hb3, hb4, hb5, hb6, hb7;
    L0_MT(0, ha0, ha1, hb0, hb1);
    L0_MT(1, ha2, ha3, hb2, hb3);
    L0_MT(2, ha4, ha5, hb4, hb5);
    L0_MT(3, ha6, ha7, hb6, hb7);

    // ---- layer 1 with fused layer 2 ----
    floatx16 acc3a = zero16();
    floatx16 acc3b = zero16();
    L1_MT(0);
    L1_MT(1);
    L1_MT(2);
    L1_MT(3);
    {
        half8 ab = LDF(53248 + 8 * 1024);
        acc3a = MFMA(ab, bbias, acc3a);
        acc3b = MFMA(ab, bbias, acc3b);
    }

    // D: col = e = ln, row = (r&3)+8*(r>>2)+4*hl -> hl=0 regs 0,1,2 are o=0,1,2
    if (hl == 0) {
        int nn = base + ln;
        if (nn < N) {
            float* op = out + ((size_t)c * N + nn) * 3;
            op[0] = acc3a[0];
            op[1] = acc3a[1];
            op[2] = acc3a[2];
        }
        nn = base + 32 + ln;
        if (nn < N) {
            float* op = out + ((size_t)c * N + nn) * 3;
            op[0] = acc3b[0];
            op[1] = acc3b[1];
            op[2] = acc3b[2];
        }
    }
}

extern "C" void kernel_launch(void* const* d_in, const int* in_sizes, int n_in,
                              void* d_out, int out_size, void* d_ws, size_t ws_size,
                              hipStream_t stream) {
    const float* feats   = (const float*)d_in[0];
    const float* dirs    = (const float*)d_in[1];
    const float* emb_tab = (const float*)d_in[2];
    const float* W0      = (const float*)d_in[3];
    const float* b0      = (const float*)d_in[4];
    const float* W1      = (const float*)d_in[5];
    const float* b1      = (const float*)d_in[6];
    const float* W2      = (const float*)d_in[7];
    const float* b2      = (const float*)d_in[8];
    const int*   eids    = (const int*)d_in[9];
    const int*   shd     = (const int*)d_in[10];
    float* outp          = (float*)d_out;

    int N = in_sizes[0] / 32;    // features [N,32]
    int C = in_sizes[9];         // embed_ids [C]

    _Float16* wsh = (_Float16*)d_ws;

    int ws_elems = C * 8192 + 23040;
    vdc_prep_kernel<<<(ws_elems + 255) / 256, 256, 0, stream>>>(
        W0, W1, W2, b0, b1, b2, emb_tab, eids, C, wsh);

    dim3 grid((N + 511) / 512, C);
    vdc_mlp_kernel<<<grid, 512, 0, stream>>>(
        feats, dirs, shd, wsh, outp, N, C);
}

// Round 12
// 170.616 us; speedup vs baseline: 1.5366x; 1.5366x over previous
//
#include <hip/hip_runtime.h>
#include <cstdint>
#include <cstddef>

typedef _Float16 half8 __attribute__((ext_vector_type(8)));
typedef __fp16 fp16x2 __attribute__((ext_vector_type(2)));
typedef float floatx16 __attribute__((ext_vector_type(16)));

// ws: frag-linear weight blobs. chunk = 1024 B = 64 lanes x 8 f16, lane l holds
// A[row = tile*32 + (l&31)][k = kchunk*16 + (l>>5)*8 + i], i=0..7.
//   W0c [C][16 chunks]  @ f16 0       (mt 0..3) x (ks 0..3); k<48: W0[(16+k)*128+j],
//                                     k==48: cbias(c,j)=b0[j]+emb_c.W0[0:16,j], else 0
//   W1  [36 chunks]     @ C*8192      (mt 0..3) x (ks 0..8); k<128: W1[k*128+j], k==128: b1[j], else 0
//   W2  [9 chunks]      @ C*8192+18432  (ks 0..8); o=(l&31): o<3 ? (k<128? W2[k*3+o] : k==128? b2[o] : 0) : 0

__global__ void vdc_prep_kernel(const float* __restrict__ W0,
                                const float* __restrict__ W1,
                                const float* __restrict__ W2,
                                const float* __restrict__ b0,
                                const float* __restrict__ b1,
                                const float* __restrict__ b2,
                                const float* __restrict__ emb_tab,
                                const int* __restrict__ embed_ids,
                                int C,
                                _Float16* __restrict__ ws) {
    int i = blockIdx.x * 256 + threadIdx.x;
    int w0end = C * 8192;
    int w1end = w0end + 18432;
    int w2end = w1end + 4608;
    float v = 0.0f;
    if (i < w0end) {
        int c = i >> 13, r = i & 8191;
        int ci = r >> 9, l = (r >> 3) & 63, ii = r & 7;
        int mt = ci >> 2, ks = ci & 3;
        int j  = mt * 32 + (l & 31);
        int kk = ks * 16 + (l >> 5) * 8 + ii;
        if (kk < 48) v = W0[(16 + kk) * 128 + j];
        else if (kk == 48) {
            int id = embed_ids[c];
            v = b0[j];
            #pragma unroll
            for (int e = 0; e < 16; ++e)
                v += emb_tab[(size_t)id * 16 + e] * W0[e * 128 + j];
        }
        ws[i] = (_Float16)v;
    } else if (i < w1end) {
        int r = i - w0end;
        int ci = r >> 9, l = (r >> 3) & 63, ii = r & 7;
        int mt = ci / 9, ks = ci - mt * 9;
        int j  = mt * 32 + (l & 31);
        int kk = ks * 16 + (l >> 5) * 8 + ii;
        if (kk < 128) v = W1[kk * 128 + j];
        else if (kk == 128) v = b1[j];
        ws[i] = (_Float16)v;
    } else if (i < w2end) {
        int r = i - w1end;
        int ks = r >> 9, l = (r >> 3) & 63, ii = r & 7;
        int o  = l & 31;
        int kk = ks * 16 + (l >> 5) * 8 + ii;
        if (o < 3) {
            if (kk < 128) v = W2[kk * 3 + o];
            else if (kk == 128) v = b2[o];
        }
        ws[i] = (_Float16)v;
    }
}

union U4 { unsigned u[4]; half8 h; };

__device__ __forceinline__ unsigned pkr(float a, float b) {
    union { fp16x2 h; unsigned u; } x;
    x.h = __builtin_amdgcn_cvt_pkrtz(a, b);
    return x.u;
}

__device__ __forceinline__ floatx16 zero16() {
    floatx16 z;
    #pragma unroll
    for (int r = 0; r < 16; ++r) z[r] = 0.0f;
    return z;
}

// acc tile (C-layout) -> two B-frag half8 chunks via relu+pack+lane^32 exchange.
__device__ __forceinline__ void transition(const floatx16& a, int hl,
                                           half8& lo, half8& hi) {
    unsigned p0 = pkr(fmaxf(a[0],  0.f), fmaxf(a[1],  0.f));
    unsigned p1 = pkr(fmaxf(a[2],  0.f), fmaxf(a[3],  0.f));
    unsigned p2 = pkr(fmaxf(a[4],  0.f), fmaxf(a[5],  0.f));
    unsigned p3 = pkr(fmaxf(a[6],  0.f), fmaxf(a[7],  0.f));
    unsigned p4 = pkr(fmaxf(a[8],  0.f), fmaxf(a[9],  0.f));
    unsigned p5 = pkr(fmaxf(a[10], 0.f), fmaxf(a[11], 0.f));
    unsigned p6 = pkr(fmaxf(a[12], 0.f), fmaxf(a[13], 0.f));
    unsigned p7 = pkr(fmaxf(a[14], 0.f), fmaxf(a[15], 0.f));
    unsigned r0 = __shfl_xor(hl ? p0 : p2, 32);
    unsigned r1 = __shfl_xor(hl ? p1 : p3, 32);
    unsigned r2 = __shfl_xor(hl ? p4 : p6, 32);
    unsigned r3 = __shfl_xor(hl ? p5 : p7, 32);
    U4 L, H;
    L.u[0] = hl ? r0 : p0;
    L.u[1] = hl ? r1 : p1;
    L.u[2] = hl ? p2 : r0;
    L.u[3] = hl ? p3 : r1;
    H.u[0] = hl ? r2 : p4;
    H.u[1] = hl ? r3 : p5;
    H.u[2] = hl ? p6 : r2;
    H.u[3] = hl ? p7 : r3;
    lo = L.h; hi = H.h;
}

// build layer0 B-operand frags (feats chunks 0,1 + SH chunk 2) for element n
__device__ __forceinline__ void build_bfrags(
    const float* __restrict__ feats, const float* __restrict__ dirs,
    size_t cN, int n, int hl, int nbu,
    half8& o0, half8& o1, half8& o2)
{
    const float* fp = feats + (size_t)n * 32 + hl * 8;
    float4 f0 = *(const float4*)(fp);
    float4 f1 = *(const float4*)(fp + 4);
    float4 f2 = *(const float4*)(fp + 16);
    float4 f3 = *(const float4*)(fp + 20);
    U4 u0, u1;
    u0.u[0] = pkr(f0.x, f0.y); u0.u[1] = pkr(f0.z, f0.w);
    u0.u[2] = pkr(f1.x, f1.y); u0.u[3] = pkr(f1.z, f1.w);
    u1.u[0] = pkr(f2.x, f2.y); u1.u[1] = pkr(f2.z, f2.w);
    u1.u[2] = pkr(f3.x, f3.y); u1.u[3] = pkr(f3.z, f3.w);
    o0 = u0.h; o1 = u1.h;

    const float* dp = dirs + (cN + n) * 3;
    float dx = dp[0], dy = dp[1], dz = dp[2];
    float nrm = sqrtf(dx * dx + dy * dy + dz * dz);
    float inv = 1.0f / fmaxf(nrm, 1e-12f);
    float x = dx * inv, y = dy * inv, z = dz * inv;

    float z2     = z * z;
    float fTmp0B = -1.092548430592079f * z;
    float fC1    = x * x - y * y;
    float fS1    = 2.0f * x * y;
    float fTmp0C = -2.285228997322329f * z2 + 0.4570457994644658f;
    float fTmp1B = 1.445305721320277f * z;
    float fC2    = x * fC1 - y * fS1;
    float fS2    = x * fS1 + y * fC1;

    float sh[16];
    sh[0]  = 0.2820947917738781f;
    sh[1]  = -0.48860251190292f * y;
    sh[2]  = 0.48860251190292f * z;
    sh[3]  = -0.48860251190292f * x;
    sh[4]  = 0.5462742152960395f * fS1;
    sh[5]  = fTmp0B * y;
    sh[6]  = 0.9461746957575601f * z2 - 0.3153915652525201f;
    sh[7]  = fTmp0B * x;
    sh[8]  = 0.5462742152960395f * fC1;
    sh[9]  = -0.5900435899266435f * fS2;
    sh[10] = fTmp1B * fS1;
    sh[11] = fTmp0C * y;
    sh[12] = z * (1.865881662950577f * z2 - 1.119528997770346f);
    sh[13] = fTmp0C * x;
    sh[14] = fTmp1B * fC1;
    sh[15] = -0.5900435899266435f * fC2;
    #pragma unroll
    for (int i = 0; i < 16; ++i) if (i >= nbu) sh[i] = 0.0f;

    float s0 = hl ? sh[8]  : sh[0];
    float s1 = hl ? sh[9]  : sh[1];
    float s2 = hl ? sh[10] : sh[2];
    float s3 = hl ? sh[11] : sh[3];
    float s4 = hl ? sh[12] : sh[4];
    float s5 = hl ? sh[13] : sh[5];
    float s6 = hl ? sh[14] : sh[6];
    float s7 = hl ? sh[15] : sh[7];
    U4 u2;
    u2.u[0] = pkr(s0, s1); u2.u[1] = pkr(s2, s3);
    u2.u[2] = pkr(s4, s5); u2.u[3] = pkr(s6, s7);
    o2 = u2.h;
}

#define MFMA(a, b, c) __builtin_amdgcn_mfma_f32_32x32x16_f16((a), (b), (c), 0, 0, 0)
#define LDF(off) (*(const half8*)(fr + (off)))
#define GW2(ch) (*(const half8*)(w2p + (ch) * 512 + lane * 8))

// layer 0, one 32-row weight tile MT, both element tiles (a and b)
#define L0_MT(MT, HA0, HA1, HB0, HB1)                                    \
    do {                                                                 \
        half8 a0 = LDF(((MT) * 4 + 0) * 1024);                           \
        half8 a1 = LDF(((MT) * 4 + 1) * 1024);                           \
        half8 a2 = LDF(((MT) * 4 + 2) * 1024);                           \
        half8 a3 = LDF(((MT) * 4 + 3) * 1024);                           \
        floatx16 acc = zero16();                                         \
        acc = MFMA(a0, ax0, acc); acc = MFMA(a1, ax1, acc);              \
        acc = MFMA(a2, ax2, acc); acc = MFMA(a3, bbias, acc);            \
        transition(acc, hl, HA0, HA1);                                   \
        acc = zero16();                                                  \
        acc = MFMA(a0, bx0, acc); acc = MFMA(a1, bx1, acc);              \
        acc = MFMA(a2, bx2, acc); acc = MFMA(a3, bbias, acc);            \
        transition(acc, hl, HB0, HB1);                                   \
    } while (0)

// layer 1 (+ fused layer 2) for one 32-row W1 tile MT, both element tiles
#define L1_MT(MT)                                                        \
    do {                                                                 \
        half8 q0 = LDF(16384 + ((MT) * 9 + 0) * 1024);                   \
        half8 q1 = LDF(16384 + ((MT) * 9 + 1) * 1024);                   \
        half8 q2 = LDF(16384 + ((MT) * 9 + 2) * 1024);                   \
        half8 q3 = LDF(16384 + ((MT) * 9 + 3) * 1024);                   \
        half8 q4 = LDF(16384 + ((MT) * 9 + 4) * 1024);                   \
        half8 q5 = LDF(16384 + ((MT) * 9 + 5) * 1024);                   \
        half8 q6 = LDF(16384 + ((MT) * 9 + 6) * 1024);                   \
        half8 q7 = LDF(16384 + ((MT) * 9 + 7) * 1024);                   \
        half8 q8 = LDF(16384 + ((MT) * 9 + 8) * 1024);                   \
        half8 w2a = GW2(2 * (MT) + 0);                                   \
        half8 w2b = GW2(2 * (MT) + 1);                                   \
        floatx16 acc = zero16();                                         \
        acc = MFMA(q0, ha0, acc); acc = MFMA(q1, ha1, acc);              \
        acc = MFMA(q2, ha2, acc); acc = MFMA(q3, ha3, acc);              \
        acc = MFMA(q4, ha4, acc); acc = MFMA(q5, ha5, acc);              \
        acc = MFMA(q6, ha6, acc); acc = MFMA(q7, ha7, acc);              \
        acc = MFMA(q8, bbias, acc);                                      \
        half8 g0, g1;                                                    \
        transition(acc, hl, g0, g1);                                     \
        acc3a = MFMA(w2a, g0, acc3a); acc3a = MFMA(w2b, g1, acc3a);      \
        acc = zero16();                                                  \
        acc = MFMA(q0, hb0, acc); acc = MFMA(q1, hb1, acc);              \
        acc = MFMA(q2, hb2, acc); acc = MFMA(q3, hb3, acc);              \
        acc = MFMA(q4, hb4, acc); acc = MFMA(q5, hb5, acc);              \
        acc = MFMA(q6, hb6, acc); acc = MFMA(q7, hb7, acc);              \
        acc = MFMA(q8, bbias, acc);                                      \
        transition(acc, hl, g0, g1);                                     \
        acc3b = MFMA(w2a, g0, acc3b); acc3b = MFMA(w2b, g1, acc3b);      \
    } while (0)

// LDS frag arena: W0c chunks 0..15 @0, W1 chunks @16384. 53248 B total.
// W2 frags read directly from global (9 KB, L1-resident across all blocks).
// 256 threads = 4 waves, EPW=2. __launch_bounds__(256,3): ~170 unified regs,
// 3 blocks/CU x 4 waves = 12 waves/CU = 3 waves/SIMD (LDS: 3*53248 <= 160K).
__global__ __launch_bounds__(256, 3) void vdc_mlp_kernel(
    const float* __restrict__ feats,      // [N,32]
    const float* __restrict__ dirs,       // [C,N,3]
    const int* __restrict__ sh_deg_p,     // [1]
    const _Float16* __restrict__ ws,
    float* __restrict__ out,              // [C,N,3]
    int N, int C)
{
    __shared__ uint4 arena[3328];         // 53248 B
    char* lds = (char*)arena;

    const int tid   = threadIdx.x;
    const int c     = blockIdx.y;
    const int w     = tid >> 6;           // 0..3
    const int lane  = tid & 63;
    const int ln    = lane & 31;
    const int hl    = lane >> 5;
    const int base  = blockIdx.x * 256 + w * 64;   // this wave's 64 elements

    const _Float16* w2p = ws + (size_t)C * 8192 + 18432;

    // ---- stage frag-linear weights into LDS (coalesced, conflict-free) ----
    {
        const uint4* srcA = (const uint4*)(ws + (size_t)c * 8192);
        const uint4* srcB = (const uint4*)(ws + (size_t)C * 8192);
        #pragma unroll
        for (int it = 0; it < 13; ++it) {
            int idx = it * 256 + tid;
            arena[idx] = (idx < 1024) ? srcA[idx] : srcB[idx - 1024];
        }
    }

    // ---- build layer0 B-frags for both element tiles (overlaps staging) ----
    half8 bbias;
    {
        U4 ub;
        ub.u[0] = hl ? 0u : 0x00003C00u;   // f16 1.0 at k-offset 0, hl=0 only
        ub.u[1] = 0u; ub.u[2] = 0u; ub.u[3] = 0u;
        bbias = ub.h;
    }
    int deg = sh_deg_p[0];
    int nbu = (deg + 1) * (deg + 1);
    int na = base + ln;      if (na >= N) na = N - 1;
    int nb = base + 32 + ln; if (nb >= N) nb = N - 1;
    half8 ax0, ax1, ax2, bx0, bx1, bx2;
    build_bfrags(feats, dirs, (size_t)c * N, na, hl, nbu, ax0, ax1, ax2);
    build_bfrags(feats, dirs, (size_t)c * N, nb, hl, nbu, bx0, bx1, bx2);

    __syncthreads();

    const char* fr = lds + lane * 16;     // per-lane frag base; chunk offsets imm

    // ---- layer 0 + transitions (named h-frags) ----
    half8 ha0, ha1, ha2, ha3, ha4, ha5, ha6, ha7;
    half8 hb0, hb1, hb2, hb3, hb4, hb5, hb6, hb7;
    L0_MT(0, ha0, ha1, hb0, hb1);
    L0_MT(1, ha2, ha3, hb2, hb3);
    L0_MT(2, ha4, ha5, hb4, hb5);
    L0_MT(3, ha6, ha7, hb6, hb7);

    // ---- layer 1 with fused layer 2 ----
    floatx16 acc3a = zero16();
    floatx16 acc3b = zero16();
    L1_MT(0);
    L1_MT(1);
    L1_MT(2);
    L1_MT(3);
    {
        half8 ab = GW2(8);
        acc3a = MFMA(ab, bbias, acc3a);
        acc3b = MFMA(ab, bbias, acc3b);
    }

    // D: col = e = ln, row = (r&3)+8*(r>>2)+4*hl -> hl=0 regs 0,1,2 are o=0,1,2
    if (hl == 0) {
        int nn = base + ln;
        if (nn < N) {
            float* op = out + ((size_t)c * N + nn) * 3;
            op[0] = acc3a[0];
            op[1] = acc3a[1];
            op[2] = acc3a[2];
        }
        nn = base + 32 + ln;
        if (nn < N) {
            float* op = out + ((size_t)c * N + nn) * 3;
            op[0] = acc3b[0];
            op[1] = acc3b[1];
            op[2] = acc3b[2];
        }
    }
}

extern "C" void kernel_launch(void* const* d_in, const int* in_sizes, int n_in,
                              void* d_out, int out_size, void* d_ws, size_t ws_size,
                              hipStream_t stream) {
    const float* feats   = (const float*)d_in[0];
    const float* dirs    = (const float*)d_in[1];
    const float* emb_tab = (const float*)d_in[2];
    const float* W0      = (const float*)d_in[3];
    const float* b0      = (const float*)d_in[4];
    const float* W1      = (const float*)d_in[5];
    const float* b1      = (const float*)d_in[6];
    const float* W2      = (const float*)d_in[7];
    const float* b2      = (const float*)d_in[8];
    const int*   eids    = (const int*)d_in[9];
    const int*   shd     = (const int*)d_in[10];
    float* outp          = (float*)d_out;

    int N = in_sizes[0] / 32;    // features [N,32]
    int C = in_sizes[9];         // embed_ids [C]

    _Float16* wsh = (_Float16*)d_ws;

    int ws_elems = C * 8192 + 23040;
    vdc_prep_kernel<<<(ws_elems + 255) / 256, 256, 0, stream>>>(
        W0, W1, W2, b0, b1, b2, emb_tab, eids, C, wsh);

    dim3 grid((N + 255) / 256, C);
    vdc_mlp_kernel<<<grid, 256, 0, stream>>>(
        feats, dirs, shd, wsh, outp, N, C);
}

// Round 13
// 158.510 us; speedup vs baseline: 1.6540x; 1.0764x over previous
//
#include <hip/hip_runtime.h>
#include <cstdint>
#include <cstddef>

typedef _Float16 half8 __attribute__((ext_vector_type(8)));
typedef __fp16 fp16x2 __attribute__((ext_vector_type(2)));
typedef float floatx16 __attribute__((ext_vector_type(16)));

// ws: frag-linear weight blobs. chunk = 1024 B = 64 lanes x 8 f16, lane l holds
// A[row = tile*32 + (l&31)][k = kchunk*16 + (l>>5)*8 + i], i=0..7.
//   W0c [C][16 chunks]  @ f16 0       (mt 0..3) x (ks 0..3); k<48: W0[(16+k)*128+j],
//                                     k==48: cbias(c,j)=b0[j]+emb_c.W0[0:16,j], else 0
//   W1  [36 chunks]     @ C*8192      (mt 0..3) x (ks 0..8); k<128: W1[k*128+j], k==128: b1[j], else 0
//   W2  [9 chunks]      @ C*8192+18432  (ks 0..8); o=(l&31): o<3 ? (k<128? W2[k*3+o] : k==128? b2[o] : 0) : 0

__global__ void vdc_prep_kernel(const float* __restrict__ W0,
                                const float* __restrict__ W1,
                                const float* __restrict__ W2,
                                const float* __restrict__ b0,
                                const float* __restrict__ b1,
                                const float* __restrict__ b2,
                                const float* __restrict__ emb_tab,
                                const int* __restrict__ embed_ids,
                                int C,
                                _Float16* __restrict__ ws) {
    int i = blockIdx.x * 256 + threadIdx.x;
    int w0end = C * 8192;
    int w1end = w0end + 18432;
    int w2end = w1end + 4608;
    float v = 0.0f;
    if (i < w0end) {
        int c = i >> 13, r = i & 8191;
        int ci = r >> 9, l = (r >> 3) & 63, ii = r & 7;
        int mt = ci >> 2, ks = ci & 3;
        int j  = mt * 32 + (l & 31);
        int kk = ks * 16 + (l >> 5) * 8 + ii;
        if (kk < 48) v = W0[(16 + kk) * 128 + j];
        else if (kk == 48) {
            int id = embed_ids[c];
            v = b0[j];
            #pragma unroll
            for (int e = 0; e < 16; ++e)
                v += emb_tab[(size_t)id * 16 + e] * W0[e * 128 + j];
        }
        ws[i] = (_Float16)v;
    } else if (i < w1end) {
        int r = i - w0end;
        int ci = r >> 9, l = (r >> 3) & 63, ii = r & 7;
        int mt = ci / 9, ks = ci - mt * 9;
        int j  = mt * 32 + (l & 31);
        int kk = ks * 16 + (l >> 5) * 8 + ii;
        if (kk < 128) v = W1[kk * 128 + j];
        else if (kk == 128) v = b1[j];
        ws[i] = (_Float16)v;
    } else if (i < w2end) {
        int r = i - w1end;
        int ks = r >> 9, l = (r >> 3) & 63, ii = r & 7;
        int o  = l & 31;
        int kk = ks * 16 + (l >> 5) * 8 + ii;
        if (o < 3) {
            if (kk < 128) v = W2[kk * 3 + o];
            else if (kk == 128) v = b2[o];
        }
        ws[i] = (_Float16)v;
    }
}

union U4 { unsigned u[4]; half8 h; };

__device__ __forceinline__ unsigned pkr(float a, float b) {
    union { fp16x2 h; unsigned u; } x;
    x.h = __builtin_amdgcn_cvt_pkrtz(a, b);
    return x.u;
}

__device__ __forceinline__ floatx16 zero16() {
    floatx16 z;
    #pragma unroll
    for (int r = 0; r < 16; ++r) z[r] = 0.0f;
    return z;
}

// acc tile (C-layout) -> two B-frag half8 chunks via relu+pack+lane^32 exchange.
__device__ __forceinline__ void transition(const floatx16& a, int hl,
                                           half8& lo, half8& hi) {
    unsigned p0 = pkr(fmaxf(a[0],  0.f), fmaxf(a[1],  0.f));
    unsigned p1 = pkr(fmaxf(a[2],  0.f), fmaxf(a[3],  0.f));
    unsigned p2 = pkr(fmaxf(a[4],  0.f), fmaxf(a[5],  0.f));
    unsigned p3 = pkr(fmaxf(a[6],  0.f), fmaxf(a[7],  0.f));
    unsigned p4 = pkr(fmaxf(a[8],  0.f), fmaxf(a[9],  0.f));
    unsigned p5 = pkr(fmaxf(a[10], 0.f), fmaxf(a[11], 0.f));
    unsigned p6 = pkr(fmaxf(a[12], 0.f), fmaxf(a[13], 0.f));
    unsigned p7 = pkr(fmaxf(a[14], 0.f), fmaxf(a[15], 0.f));
    unsigned r0 = __shfl_xor(hl ? p0 : p2, 32);
    unsigned r1 = __shfl_xor(hl ? p1 : p3, 32);
    unsigned r2 = __shfl_xor(hl ? p4 : p6, 32);
    unsigned r3 = __shfl_xor(hl ? p5 : p7, 32);
    U4 L, H;
    L.u[0] = hl ? r0 : p0;
    L.u[1] = hl ? r1 : p1;
    L.u[2] = hl ? p2 : r0;
    L.u[3] = hl ? p3 : r1;
    H.u[0] = hl ? r2 : p4;
    H.u[1] = hl ? r3 : p5;
    H.u[2] = hl ? p6 : r2;
    H.u[3] = hl ? p7 : r3;
    lo = L.h; hi = H.h;
}

// build layer0 B-operand frags (feats chunks 0,1 + SH chunk 2) for element n
__device__ __forceinline__ void build_bfrags(
    const float* __restrict__ feats, const float* __restrict__ dirs,
    size_t cN, int n, int hl, int nbu,
    half8& o0, half8& o1, half8& o2)
{
    const float* fp = feats + (size_t)n * 32 + hl * 8;
    float4 f0 = *(const float4*)(fp);
    float4 f1 = *(const float4*)(fp + 4);
    float4 f2 = *(const float4*)(fp + 16);
    float4 f3 = *(const float4*)(fp + 20);
    U4 u0, u1;
    u0.u[0] = pkr(f0.x, f0.y); u0.u[1] = pkr(f0.z, f0.w);
    u0.u[2] = pkr(f1.x, f1.y); u0.u[3] = pkr(f1.z, f1.w);
    u1.u[0] = pkr(f2.x, f2.y); u1.u[1] = pkr(f2.z, f2.w);
    u1.u[2] = pkr(f3.x, f3.y); u1.u[3] = pkr(f3.z, f3.w);
    o0 = u0.h; o1 = u1.h;

    const float* dp = dirs + (cN + n) * 3;
    float dx = dp[0], dy = dp[1], dz = dp[2];
    float nrm = sqrtf(dx * dx + dy * dy + dz * dz);
    float inv = 1.0f / fmaxf(nrm, 1e-12f);
    float x = dx * inv, y = dy * inv, z = dz * inv;

    float z2     = z * z;
    float fTmp0B = -1.092548430592079f * z;
    float fC1    = x * x - y * y;
    float fS1    = 2.0f * x * y;
    float fTmp0C = -2.285228997322329f * z2 + 0.4570457994644658f;
    float fTmp1B = 1.445305721320277f * z;
    float fC2    = x * fC1 - y * fS1;
    float fS2    = x * fS1 + y * fC1;

    float sh[16];
    sh[0]  = 0.2820947917738781f;
    sh[1]  = -0.48860251190292f * y;
    sh[2]  = 0.48860251190292f * z;
    sh[3]  = -0.48860251190292f * x;
    sh[4]  = 0.5462742152960395f * fS1;
    sh[5]  = fTmp0B * y;
    sh[6]  = 0.9461746957575601f * z2 - 0.3153915652525201f;
    sh[7]  = fTmp0B * x;
    sh[8]  = 0.5462742152960395f * fC1;
    sh[9]  = -0.5900435899266435f * fS2;
    sh[10] = fTmp1B * fS1;
    sh[11] = fTmp0C * y;
    sh[12] = z * (1.865881662950577f * z2 - 1.119528997770346f);
    sh[13] = fTmp0C * x;
    sh[14] = fTmp1B * fC1;
    sh[15] = -0.5900435899266435f * fC2;
    #pragma unroll
    for (int i = 0; i < 16; ++i) if (i >= nbu) sh[i] = 0.0f;

    float s0 = hl ? sh[8]  : sh[0];
    float s1 = hl ? sh[9]  : sh[1];
    float s2 = hl ? sh[10] : sh[2];
    float s3 = hl ? sh[11] : sh[3];
    float s4 = hl ? sh[12] : sh[4];
    float s5 = hl ? sh[13] : sh[5];
    float s6 = hl ? sh[14] : sh[6];
    float s7 = hl ? sh[15] : sh[7];
    U4 u2;
    u2.u[0] = pkr(s0, s1); u2.u[1] = pkr(s2, s3);
    u2.u[2] = pkr(s4, s5); u2.u[3] = pkr(s6, s7);
    o2 = u2.h;
}

#define MFMA(a, b, c) __builtin_amdgcn_mfma_f32_32x32x16_f16((a), (b), (c), 0, 0, 0)
#define LDF(off) (*(const half8*)(fr + (off)))
#define GW2(ch) (*(const half8*)(w2p + (ch) * 512 + lane * 8))

// layer 0, tile MT: each weight frag loaded once, consumed by both chains, dies.
#define L0_MT(MT, HA0, HA1, HB0, HB1)                                    \
    do {                                                                 \
        floatx16 ca = zero16();                                          \
        floatx16 cb = zero16();                                          \
        half8 t0 = LDF(((MT) * 4 + 0) * 1024);                           \
        ca = MFMA(t0, ax0, ca); cb = MFMA(t0, bx0, cb);                  \
        half8 t1 = LDF(((MT) * 4 + 1) * 1024);                           \
        ca = MFMA(t1, ax1, ca); cb = MFMA(t1, bx1, cb);                  \
        half8 t2 = LDF(((MT) * 4 + 2) * 1024);                           \
        ca = MFMA(t2, ax2, ca); cb = MFMA(t2, bx2, cb);                  \
        half8 t3 = LDF(((MT) * 4 + 3) * 1024);                           \
        ca = MFMA(t3, bbias, ca); cb = MFMA(t3, bbias, cb);              \
        transition(ca, hl, HA0, HA1);                                    \
        transition(cb, hl, HB0, HB1);                                    \
    } while (0)

#define L1_KS(MT, KS, HA, HB)                                            \
    do {                                                                 \
        half8 q = LDF(16384 + ((MT) * 9 + (KS)) * 1024);                 \
        ca = MFMA(q, HA, ca); cb = MFMA(q, HB, cb);                      \
    } while (0)

// layer 1 (+ fused layer 2) for one 32-row W1 tile MT, both element tiles
#define L1_MT(MT)                                                        \
    do {                                                                 \
        floatx16 ca = zero16();                                          \
        floatx16 cb = zero16();                                          \
        L1_KS(MT, 0, ha0, hb0);                                          \
        L1_KS(MT, 1, ha1, hb1);                                          \
        L1_KS(MT, 2, ha2, hb2);                                          \
        L1_KS(MT, 3, ha3, hb3);                                          \
        L1_KS(MT, 4, ha4, hb4);                                          \
        L1_KS(MT, 5, ha5, hb5);                                          \
        L1_KS(MT, 6, ha6, hb6);                                          \
        L1_KS(MT, 7, ha7, hb7);                                          \
        L1_KS(MT, 8, bbias, bbias);                                      \
        half8 w2a = GW2(2 * (MT) + 0);                                   \
        half8 w2b = GW2(2 * (MT) + 1);                                   \
        half8 g0, g1;                                                    \
        transition(ca, hl, g0, g1);                                      \
        acc3a = MFMA(w2a, g0, acc3a); acc3a = MFMA(w2b, g1, acc3a);      \
        transition(cb, hl, g0, g1);                                      \
        acc3b = MFMA(w2a, g0, acc3b); acc3b = MFMA(w2b, g1, acc3b);      \
    } while (0)

// LDS frag arena: W0c chunks 0..15 @0, W1 chunks @16384. 53248 B total.
// W2 frags read directly from global (9 KB, L1-resident across all blocks).
// 256 threads = 4 waves, EPW=2. Load-use-die weight frags cap the register
// peak at ~150 unified -> (256,3) (170-reg cap) fits with NO spill.
// 3 blocks/CU x 4 waves = 12 waves/CU (LDS: 3*53248 <= 160K).
__global__ __launch_bounds__(256, 3) void vdc_mlp_kernel(
    const float* __restrict__ feats,      // [N,32]
    const float* __restrict__ dirs,       // [C,N,3]
    const int* __restrict__ sh_deg_p,     // [1]
    const _Float16* __restrict__ ws,
    float* __restrict__ out,              // [C,N,3]
    int N, int C)
{
    __shared__ uint4 arena[3328];         // 53248 B
    char* lds = (char*)arena;

    const int tid   = threadIdx.x;
    const int c     = blockIdx.y;
    const int w     = tid >> 6;           // 0..3
    const int lane  = tid & 63;
    const int ln    = lane & 31;
    const int hl    = lane >> 5;
    const int base  = blockIdx.x * 256 + w * 64;   // this wave's 64 elements

    const _Float16* w2p = ws + (size_t)C * 8192 + 18432;

    // ---- stage frag-linear weights into LDS (coalesced, conflict-free) ----
    {
        const uint4* srcA = (const uint4*)(ws + (size_t)c * 8192);
        const uint4* srcB = (const uint4*)(ws + (size_t)C * 8192);
        #pragma unroll
        for (int it = 0; it < 13; ++it) {
            int idx = it * 256 + tid;
            arena[idx] = (idx < 1024) ? srcA[idx] : srcB[idx - 1024];
        }
    }

    // ---- build layer0 B-frags for both element tiles (overlaps staging) ----
    half8 bbias;
    {
        U4 ub;
        ub.u[0] = hl ? 0u : 0x00003C00u;   // f16 1.0 at k-offset 0, hl=0 only
        ub.u[1] = 0u; ub.u[2] = 0u; ub.u[3] = 0u;
        bbias = ub.h;
    }
    int deg = sh_deg_p[0];
    int nbu = (deg + 1) * (deg + 1);
    int na = base + ln;      if (na >= N) na = N - 1;
    int nb = base + 32 + ln; if (nb >= N) nb = N - 1;
    half8 ax0, ax1, ax2, bx0, bx1, bx2;
    build_bfrags(feats, dirs, (size_t)c * N, na, hl, nbu, ax0, ax1, ax2);
    build_bfrags(feats, dirs, (size_t)c * N, nb, hl, nbu, bx0, bx1, bx2);

    __syncthreads();

    const char* fr = lds + lane * 16;     // per-lane frag base; chunk offsets imm

    // ---- layer 0 + transitions (named h-frags) ----
    half8 ha0, ha1, ha2, ha3, ha4, ha5, ha6, ha7;
    half8 hb0, hb1, hb2, hb3, hb4, hb5, hb6, hb7;
    L0_MT(0, ha0, ha1, hb0, hb1);
    L0_MT(1, ha2, ha3, hb2, hb3);
    L0_MT(2, ha4, ha5, hb4, hb5);
    L0_MT(3, ha6, ha7, hb6, hb7);

    // ---- layer 1 with fused layer 2 ----
    floatx16 acc3a = zero16();
    floatx16 acc3b = zero16();
    L1_MT(0);
    L1_MT(1);
    L1_MT(2);
    L1_MT(3);
    {
        half8 ab = GW2(8);
        acc3a = MFMA(ab, bbias, acc3a);
        acc3b = MFMA(ab, bbias, acc3b);
    }

    // D: col = e = ln, row = (r&3)+8*(r>>2)+4*hl -> hl=0 regs 0,1,2 are o=0,1,2
    if (hl == 0) {
        int nn = base + ln;
        if (nn < N) {
            float* op = out + ((size_t)c * N + nn) * 3;
            op[0] = acc3a[0];
            op[1] = acc3a[1];
            op[2] = acc3a[2];
        }
        nn = base + 32 + ln;
        if (nn < N) {
            float* op = out + ((size_t)c * N + nn) * 3;
            op[0] = acc3b[0];
            op[1] = acc3b[1];
            op[2] = acc3b[2];
        }
    }
}

extern "C" void kernel_launch(void* const* d_in, const int* in_sizes, int n_in,
                              void* d_out, int out_size, void* d_ws, size_t ws_size,
                              hipStream_t stream) {
    const float* feats   = (const float*)d_in[0];
    const float* dirs    = (const float*)d_in[1];
    const float* emb_tab = (const float*)d_in[2];
    const float* W0      = (const float*)d_in[3];
    const float* b0      = (const float*)d_in[4];
    const float* W1      = (const float*)d_in[5];
    const float* b1      = (const float*)d_in[6];
    const float* W2      = (const float*)d_in[7];
    const float* b2      = (const float*)d_in[8];
    const int*   eids    = (const int*)d_in[9];
    const int*   shd     = (const int*)d_in[10];
    float* outp          = (float*)d_out;

    int N = in_sizes[0] / 32;    // features [N,32]
    int C = in_sizes[9];         // embed_ids [C]

    _Float16* wsh = (_Float16*)d_ws;

    int ws_elems = C * 8192 + 23040;
    vdc_prep_kernel<<<(ws_elems + 255) / 256, 256, 0, stream>>>(
        W0, W1, W2, b0, b1, b2, emb_tab, eids, C, wsh);

    dim3 grid((N + 255) / 256, C);
    vdc_mlp_kernel<<<grid, 256, 0, stream>>>(
        feats, dirs, shd, wsh, outp, N, C);
}

// Round 14
// 147.294 us; speedup vs baseline: 1.7799x; 1.0761x over previous
//
#include <hip/hip_runtime.h>
#include <cstdint>
#include <cstddef>

typedef _Float16 half8 __attribute__((ext_vector_type(8)));
typedef __fp16 fp16x2 __attribute__((ext_vector_type(2)));
typedef float floatx16 __attribute__((ext_vector_type(16)));
typedef unsigned uint2v __attribute__((ext_vector_type(2)));

// ws: frag-linear weight blobs. chunk = 1024 B = 64 lanes x 8 f16, lane l holds
// A[row = tile*32 + (l&31)][k = kchunk*16 + (l>>5)*8 + i], i=0..7.
//   W0c [C][16 chunks]  @ f16 0       (mt 0..3) x (ks 0..3); k<48: W0[(16+k)*128+j],
//                                     k==48: cbias(c,j)=b0[j]+emb_c.W0[0:16,j], else 0
//   W1  [36 chunks]     @ C*8192      (mt 0..3) x (ks 0..8); k<128: W1[k*128+j], k==128: b1[j], else 0
//   W2  [9 chunks]      @ C*8192+18432  (ks 0..8); o=(l&31): o<3 ? (k<128? W2[k*3+o] : k==128? b2[o] : 0) : 0

__global__ void vdc_prep_kernel(const float* __restrict__ W0,
                                const float* __restrict__ W1,
                                const float* __restrict__ W2,
                                const float* __restrict__ b0,
                                const float* __restrict__ b1,
                                const float* __restrict__ b2,
                                const float* __restrict__ emb_tab,
                                const int* __restrict__ embed_ids,
                                int C,
                                _Float16* __restrict__ ws) {
    int i = blockIdx.x * 256 + threadIdx.x;
    int w0end = C * 8192;
    int w1end = w0end + 18432;
    int w2end = w1end + 4608;
    float v = 0.0f;
    if (i < w0end) {
        int c = i >> 13, r = i & 8191;
        int ci = r >> 9, l = (r >> 3) & 63, ii = r & 7;
        int mt = ci >> 2, ks = ci & 3;
        int j  = mt * 32 + (l & 31);
        int kk = ks * 16 + (l >> 5) * 8 + ii;
        if (kk < 48) v = W0[(16 + kk) * 128 + j];
        else if (kk == 48) {
            int id = embed_ids[c];
            v = b0[j];
            #pragma unroll
            for (int e = 0; e < 16; ++e)
                v += emb_tab[(size_t)id * 16 + e] * W0[e * 128 + j];
        }
        ws[i] = (_Float16)v;
    } else if (i < w1end) {
        int r = i - w0end;
        int ci = r >> 9, l = (r >> 3) & 63, ii = r & 7;
        int mt = ci / 9, ks = ci - mt * 9;
        int j  = mt * 32 + (l & 31);
        int kk = ks * 16 + (l >> 5) * 8 + ii;
        if (kk < 128) v = W1[kk * 128 + j];
        else if (kk == 128) v = b1[j];
        ws[i] = (_Float16)v;
    } else if (i < w2end) {
        int r = i - w1end;
        int ks = r >> 9, l = (r >> 3) & 63, ii = r & 7;
        int o  = l & 31;
        int kk = ks * 16 + (l >> 5) * 8 + ii;
        if (o < 3) {
            if (kk < 128) v = W2[kk * 3 + o];
            else if (kk == 128) v = b2[o];
        }
        ws[i] = (_Float16)v;
    }
}

union U4 { unsigned u[4]; half8 h; };

__device__ __forceinline__ unsigned pkr(float a, float b) {
    union { fp16x2 h; unsigned u; } x;
    x.h = __builtin_amdgcn_cvt_pkrtz(a, b);
    return x.u;
}

// pack with round-toward-zero, then clamp both f16 halves to >= 0 (one v_pk_max_f16)
__device__ __forceinline__ unsigned pkrelu(float a, float b) {
    union { fp16x2 h; unsigned u; } x;
    x.h = __builtin_amdgcn_cvt_pkrtz(a, b);
    fp16x2 z = {(__fp16)0.0f, (__fp16)0.0f};
    x.h = __builtin_elementwise_max(x.h, z);
    return x.u;
}

__device__ __forceinline__ floatx16 zero16() {
    floatx16 z;
    #pragma unroll
    for (int r = 0; r < 16; ++r) z[r] = 0.0f;
    return z;
}

// acc tile (C-layout) -> two B-frag half8 chunks (relu + pack + half-wave exchange).
// gfx950 v_permlane32_swap_b32: swap(x,y) -> {[x_lo,y_lo],[x_hi,y_hi]} — exactly
// the L/H recombination; replaces ds_bpermute+cndmask per pair.
__device__ __forceinline__ void transition(const floatx16& a, int hl,
                                           half8& lo, half8& hi) {
    unsigned p0 = pkrelu(a[0],  a[1]);
    unsigned p1 = pkrelu(a[2],  a[3]);
    unsigned p2 = pkrelu(a[4],  a[5]);
    unsigned p3 = pkrelu(a[6],  a[7]);
    unsigned p4 = pkrelu(a[8],  a[9]);
    unsigned p5 = pkrelu(a[10], a[11]);
    unsigned p6 = pkrelu(a[12], a[13]);
    unsigned p7 = pkrelu(a[14], a[15]);
    U4 L, H;
#if __has_builtin(__builtin_amdgcn_permlane32_swap)
    uint2v s02 = __builtin_amdgcn_permlane32_swap(p0, p2, false, false);
    uint2v s13 = __builtin_amdgcn_permlane32_swap(p1, p3, false, false);
    uint2v s46 = __builtin_amdgcn_permlane32_swap(p4, p6, false, false);
    uint2v s57 = __builtin_amdgcn_permlane32_swap(p5, p7, false, false);
    L.u[0] = s02[0]; L.u[1] = s13[0]; L.u[2] = s02[1]; L.u[3] = s13[1];
    H.u[0] = s46[0]; H.u[1] = s57[0]; H.u[2] = s46[1]; H.u[3] = s57[1];
    (void)hl;
#else
    unsigned r0 = __shfl_xor(hl ? p0 : p2, 32);
    unsigned r1 = __shfl_xor(hl ? p1 : p3, 32);
    unsigned r2 = __shfl_xor(hl ? p4 : p6, 32);
    unsigned r3 = __shfl_xor(hl ? p5 : p7, 32);
    L.u[0] = hl ? r0 : p0;
    L.u[1] = hl ? r1 : p1;
    L.u[2] = hl ? p2 : r0;
    L.u[3] = hl ? p3 : r1;
    H.u[0] = hl ? r2 : p4;
    H.u[1] = hl ? r3 : p5;
    H.u[2] = hl ? p6 : r2;
    H.u[3] = hl ? p7 : r3;
#endif
    lo = L.h; hi = H.h;
}

// build layer0 B-operand frags (feats chunks 0,1 + SH chunk 2) for element n
__device__ __forceinline__ void build_bfrags(
    const float* __restrict__ feats, const float* __restrict__ dirs,
    size_t cN, int n, int hl, int nbu,
    half8& o0, half8& o1, half8& o2)
{
    const float* fp = feats + (size_t)n * 32 + hl * 8;
    float4 f0 = *(const float4*)(fp);
    float4 f1 = *(const float4*)(fp + 4);
    float4 f2 = *(const float4*)(fp + 16);
    float4 f3 = *(const float4*)(fp + 20);
    U4 u0, u1;
    u0.u[0] = pkr(f0.x, f0.y); u0.u[1] = pkr(f0.z, f0.w);
    u0.u[2] = pkr(f1.x, f1.y); u0.u[3] = pkr(f1.z, f1.w);
    u1.u[0] = pkr(f2.x, f2.y); u1.u[1] = pkr(f2.z, f2.w);
    u1.u[2] = pkr(f3.x, f3.y); u1.u[3] = pkr(f3.z, f3.w);
    o0 = u0.h; o1 = u1.h;

    const float* dp = dirs + (cN + n) * 3;
    float dx = dp[0], dy = dp[1], dz = dp[2];
    float nrm = sqrtf(dx * dx + dy * dy + dz * dz);
    float inv = 1.0f / fmaxf(nrm, 1e-12f);
    float x = dx * inv, y = dy * inv, z = dz * inv;

    float z2     = z * z;
    float fTmp0B = -1.092548430592079f * z;
    float fC1    = x * x - y * y;
    float fS1    = 2.0f * x * y;
    float fTmp0C = -2.285228997322329f * z2 + 0.4570457994644658f;
    float fTmp1B = 1.445305721320277f * z;
    float fC2    = x * fC1 - y * fS1;
    float fS2    = x * fS1 + y * fC1;

    float sh[16];
    sh[0]  = 0.2820947917738781f;
    sh[1]  = -0.48860251190292f * y;
    sh[2]  = 0.48860251190292f * z;
    sh[3]  = -0.48860251190292f * x;
    sh[4]  = 0.5462742152960395f * fS1;
    sh[5]  = fTmp0B * y;
    sh[6]  = 0.9461746957575601f * z2 - 0.3153915652525201f;
    sh[7]  = fTmp0B * x;
    sh[8]  = 0.5462742152960395f * fC1;
    sh[9]  = -0.5900435899266435f * fS2;
    sh[10] = fTmp1B * fS1;
    sh[11] = fTmp0C * y;
    sh[12] = z * (1.865881662950577f * z2 - 1.119528997770346f);
    sh[13] = fTmp0C * x;
    sh[14] = fTmp1B * fC1;
    sh[15] = -0.5900435899266435f * fC2;
    #pragma unroll
    for (int i = 0; i < 16; ++i) if (i >= nbu) sh[i] = 0.0f;

    float s0 = hl ? sh[8]  : sh[0];
    float s1 = hl ? sh[9]  : sh[1];
    float s2 = hl ? sh[10] : sh[2];
    float s3 = hl ? sh[11] : sh[3];
    float s4 = hl ? sh[12] : sh[4];
    float s5 = hl ? sh[13] : sh[5];
    float s6 = hl ? sh[14] : sh[6];
    float s7 = hl ? sh[15] : sh[7];
    U4 u2;
    u2.u[0] = pkr(s0, s1); u2.u[1] = pkr(s2, s3);
    u2.u[2] = pkr(s4, s5); u2.u[3] = pkr(s6, s7);
    o2 = u2.h;
}

#define MFMA(a, b, c) __builtin_amdgcn_mfma_f32_32x32x16_f16((a), (b), (c), 0, 0, 0)
#define LDF(off) (*(const half8*)(fr + (off)))
#define GW2(ch) (*(const half8*)(w2p + (ch) * 512 + lane * 8))

// layer 0, tile MT: each weight frag loaded once, consumed by both chains, dies.
#define L0_MT(MT, HA0, HA1, HB0, HB1)                                    \
    do {                                                                 \
        floatx16 ca = zero16();                                          \
        floatx16 cb = zero16();                                          \
        half8 t0 = LDF(((MT) * 4 + 0) * 1024);                           \
        ca = MFMA(t0, ax0, ca); cb = MFMA(t0, bx0, cb);                  \
        half8 t1 = LDF(((MT) * 4 + 1) * 1024);                           \
        ca = MFMA(t1, ax1, ca); cb = MFMA(t1, bx1, cb);                  \
        half8 t2 = LDF(((MT) * 4 + 2) * 1024);                           \
        ca = MFMA(t2, ax2, ca); cb = MFMA(t2, bx2, cb);                  \
        half8 t3 = LDF(((MT) * 4 + 3) * 1024);                           \
        ca = MFMA(t3, bbias, ca); cb = MFMA(t3, bbias, cb);              \
        transition(ca, hl, HA0, HA1);                                    \
        transition(cb, hl, HB0, HB1);                                    \
    } while (0)

#define L1_KS(MT, KS, HA, HB)                                            \
    do {                                                                 \
        half8 q = LDF(16384 + ((MT) * 9 + (KS)) * 1024);                 \
        ca = MFMA(q, HA, ca); cb = MFMA(q, HB, cb);                      \
    } while (0)

// layer 1 (+ fused layer 2) for one 32-row W1 tile MT, both element tiles
#define L1_MT(MT)                                                        \
    do {                                                                 \
        floatx16 ca = zero16();                                          \
        floatx16 cb = zero16();                                          \
        L1_KS(MT, 0, ha0, hb0);                                          \
        L1_KS(MT, 1, ha1, hb1);                                          \
        L1_KS(MT, 2, ha2, hb2);                                          \
        L1_KS(MT, 3, ha3, hb3);                                          \
        L1_KS(MT, 4, ha4, hb4);                                          \
        L1_KS(MT, 5, ha5, hb5);                                          \
        L1_KS(MT, 6, ha6, hb6);                                          \
        L1_KS(MT, 7, ha7, hb7);                                          \
        L1_KS(MT, 8, bbias, bbias);                                      \
        half8 w2a = GW2(2 * (MT) + 0);                                   \
        half8 w2b = GW2(2 * (MT) + 1);                                   \
        half8 g0, g1;                                                    \
        transition(ca, hl, g0, g1);                                      \
        acc3a = MFMA(w2a, g0, acc3a); acc3a = MFMA(w2b, g1, acc3a);      \
        transition(cb, hl, g0, g1);                                      \
        acc3b = MFMA(w2a, g0, acc3b); acc3b = MFMA(w2b, g1, acc3b);      \
    } while (0)

// LDS frag arena: W0c chunks 0..15 @0, W1 chunks @16384. 53248 B total.
// W2 frags read directly from global (9 KB, L1-resident across all blocks).
// 256 threads = 4 waves, EPW=2, load-use-die weight frags, (256,3) -> no spill,
// 3 blocks/CU x 4 waves = 12 waves/CU (LDS: 3*53248 <= 160K).
__global__ __launch_bounds__(256, 3) void vdc_mlp_kernel(
    const float* __restrict__ feats,      // [N,32]
    const float* __restrict__ dirs,       // [C,N,3]
    const int* __restrict__ sh_deg_p,     // [1]
    const _Float16* __restrict__ ws,
    float* __restrict__ out,              // [C,N,3]
    int N, int C)
{
    __shared__ uint4 arena[3328];         // 53248 B
    char* lds = (char*)arena;

    const int tid   = threadIdx.x;
    const int c     = blockIdx.y;
    const int w     = tid >> 6;           // 0..3
    const int lane  = tid & 63;
    const int ln    = lane & 31;
    const int hl    = lane >> 5;
    const int base  = blockIdx.x * 256 + w * 64;   // this wave's 64 elements

    const _Float16* w2p = ws + (size_t)C * 8192 + 18432;

    // ---- stage frag-linear weights into LDS (coalesced, conflict-free) ----
    {
        const uint4* srcA = (const uint4*)(ws + (size_t)c * 8192);
        const uint4* srcB = (const uint4*)(ws + (size_t)C * 8192);
        #pragma unroll
        for (int it = 0; it < 13; ++it) {
            int idx = it * 256 + tid;
            arena[idx] = (idx < 1024) ? srcA[idx] : srcB[idx - 1024];
        }
    }

    // ---- build layer0 B-frags for both element tiles (overlaps staging) ----
    half8 bbias;
    {
        U4 ub;
        ub.u[0] = hl ? 0u : 0x00003C00u;   // f16 1.0 at k-offset 0, hl=0 only
        ub.u[1] = 0u; ub.u[2] = 0u; ub.u[3] = 0u;
        bbias = ub.h;
    }
    int deg = sh_deg_p[0];
    int nbu = (deg + 1) * (deg + 1);
    int na = base + ln;      if (na >= N) na = N - 1;
    int nb = base + 32 + ln; if (nb >= N) nb = N - 1;
    half8 ax0, ax1, ax2, bx0, bx1, bx2;
    build_bfrags(feats, dirs, (size_t)c * N, na, hl, nbu, ax0, ax1, ax2);
    build_bfrags(feats, dirs, (size_t)c * N, nb, hl, nbu, bx0, bx1, bx2);

    __syncthreads();

    const char* fr = lds + lane * 16;     // per-lane frag base; chunk offsets imm

    // ---- layer 0 + transitions (named h-frags) ----
    half8 ha0, ha1, ha2, ha3, ha4, ha5, ha6, ha7;
    half8 hb0, hb1, hb2, hb3, hb4, hb5, hb6, hb7;
    L0_MT(0, ha0, ha1, hb0, hb1);
    L0_MT(1, ha2, ha3, hb2, hb3);
    L0_MT(2, ha4, ha5, hb4, hb5);
    L0_MT(3, ha6, ha7, hb6, hb7);

    // ---- layer 1 with fused layer 2 ----
    floatx16 acc3a = zero16();
    floatx16 acc3b = zero16();
    L1_MT(0);
    L1_MT(1);
    L1_MT(2);
    L1_MT(3);
    {
        half8 ab = GW2(8);
        acc3a = MFMA(ab, bbias, acc3a);
        acc3b = MFMA(ab, bbias, acc3b);
    }

    // D: col = e = ln, row = (r&3)+8*(r>>2)+4*hl -> hl=0 regs 0,1,2 are o=0,1,2
    if (hl == 0) {
        int nn = base + ln;
        if (nn < N) {
            float* op = out + ((size_t)c * N + nn) * 3;
            op[0] = acc3a[0];
            op[1] = acc3a[1];
            op[2] = acc3a[2];
        }
        nn = base + 32 + ln;
        if (nn < N) {
            float* op = out + ((size_t)c * N + nn) * 3;
            op[0] = acc3b[0];
            op[1] = acc3b[1];
            op[2] = acc3b[2];
        }
    }
}

extern "C" void kernel_launch(void* const* d_in, const int* in_sizes, int n_in,
                              void* d_out, int out_size, void* d_ws, size_t ws_size,
                              hipStream_t stream) {
    const float* feats   = (const float*)d_in[0];
    const float* dirs    = (const float*)d_in[1];
    const float* emb_tab = (const float*)d_in[2];
    const float* W0      = (const float*)d_in[3];
    const float* b0      = (const float*)d_in[4];
    const float* W1      = (const float*)d_in[5];
    const float* b1      = (const float*)d_in[6];
    const float* W2      = (const float*)d_in[7];
    const float* b2      = (const float*)d_in[8];
    const int*   eids    = (const int*)d_in[9];
    const int*   shd     = (const int*)d_in[10];
    float* outp          = (float*)d_out;

    int N = in_sizes[0] / 32;    // features [N,32]
    int C = in_sizes[9];         // embed_ids [C]

    _Float16* wsh = (_Float16*)d_ws;

    int ws_elems = C * 8192 + 23040;
    vdc_prep_kernel<<<(ws_elems + 255) / 256, 256, 0, stream>>>(
        W0, W1, W2, b0, b1, b2, emb_tab, eids, C, wsh);

    dim3 grid((N + 255) / 256, C);
    vdc_mlp_kernel<<<grid, 256, 0, stream>>>(
        feats, dirs, shd, wsh, outp, N, C);
}